// Round 3
// baseline (169.392 us; speedup 1.0000x reference)
//
#include <hip/hip_runtime.h>

// Depthwise 3D Gaussian conv (1,3,160,160,160) fp32, K=25, radius=12.
// Separable. Two main kernels:
//   conv_wh: fused W+H pass per (c,d,h-half), LDS holds W-conv result.
//   conv_dp: streaming D pass, no LDS, 20 d-outputs/thread register window.

#define NV 160
constexpr int KS    = 25;
constexpr int RAD   = 12;
constexpr int PLANE = NV * NV;        // 25600
constexpr int VOL   = NV * NV * NV;   // 4,096,000
constexpr int TOT   = 3 * VOL;        // 12,288,000

// conv_wh geometry
constexpr int HH    = 80;             // h-half
constexpr int BR    = HH + 2 * RAD;   // 104 LDS rows
constexpr int NT    = 5;              // 5 w-tiles of 32
constexpr int TP    = 17;             // float2 pitch per tile row
constexpr int OPT   = 10;             // h outputs/thread (phase 2)
constexpr int WIN   = OPT + KS - 1;   // 34
constexpr int SEG   = 16;             // w outputs/task (phase 1)
constexpr int NSEG  = NV / SEG;       // 10
constexpr int P1T   = BR * NSEG;      // 1040 phase-1 tasks

// conv_dp geometry
constexpr int DSEG  = 20;             // d outputs/thread
constexpr int NDC   = NV / DSEG;      // 8 d-chunks
constexpr int DWIN  = DSEG + KS - 1;  // 44

__device__ __forceinline__ float2 pkfma(float2 acc, float2 g2, float2 v) {
    asm("v_pk_fma_f32 %0, %1, %2, %0" : "+v"(acc) : "v"(g2), "v"(v));
    return acc;
}

// g1[i] = sum_{j,k} g3[i,j,k]  (since sum(g1)=1).
__global__ void extract_g1(const float* __restrict__ k3, float* __restrict__ g1) {
    int i = blockIdx.x;
    int t = threadIdx.x;
    float s = 0.f;
    for (int e = t; e < KS * KS; e += 64) s += k3[i * KS * KS + e];
#pragma unroll
    for (int off = 32; off > 0; off >>= 1) s += __shfl_down(s, off);
    if (t == 0) g1[i] = s;
}

// ---------------- fused W+H pass ----------------
// block = (c,d-plane, h-half). Phase 1: W conv from global (register window)
// into LDS B[5][104][17] float2. Phase 2: H conv from LDS, 10 h x 2 w per thr.
__global__ __launch_bounds__(640) void conv_wh(const float* __restrict__ in,
                                               float* __restrict__ out,
                                               const float* __restrict__ g1) {
    __shared__ float2 B[NT][BR][TP];
    float g[KS];
#pragma unroll
    for (int t = 0; t < KS; ++t) g[t] = g1[t];

    int tid  = threadIdx.x;
    int b    = blockIdx.x;
    int half = b & 1;
    int cd   = b >> 1;               // c*160 + d
    int h0   = half * HH;
    const float* base = in + (size_t)cd * PLANE;

    // ---- phase 1: W conv ----
#pragma unroll
    for (int iter = 0; iter < 2; ++iter) {
        int task = iter * 640 + tid;
        if (task < P1T) {
            int r = task % BR;       // LDS row (lanes consecutive in r)
            int s = task / BR;       // w segment
            int h = h0 + r - RAD;
            int ts    = s >> 1;
            int pbase = (s & 1) * 8; // pair offset within tile
            if (h < 0 || h >= NV) {
                float2 z = make_float2(0.f, 0.f);
#pragma unroll
                for (int u = 0; u < 8; ++u) B[ts][r][pbase + u] = z;
            } else {
                const float* rp = base + h * NV;
                float buf[SEG + 28];     // covers w' in [16s-16, 16s+28)
#pragma unroll
                for (int f = 0; f < 11; ++f) {
                    int lo = SEG * s - 16 + 4 * f;
                    if (lo >= 0 && lo <= NV - 4) {
                        const float4 v = *(const float4*)(rp + lo);
                        buf[4*f+0] = v.x; buf[4*f+1] = v.y;
                        buf[4*f+2] = v.z; buf[4*f+3] = v.w;
                    } else {
                        buf[4*f+0] = 0.f; buf[4*f+1] = 0.f;
                        buf[4*f+2] = 0.f; buf[4*f+3] = 0.f;
                    }
                }
                float2 a[8];
#pragma unroll
                for (int u = 0; u < 8; ++u) a[u] = make_float2(0.f, 0.f);
#pragma unroll
                for (int t = 0; t < KS; ++t) {
                    float2 gg = make_float2(g[t], g[t]);
#pragma unroll
                    for (int u = 0; u < 8; ++u) {
                        float2 v = make_float2(buf[2*u + t + 4], buf[2*u + t + 5]);
                        a[u] = pkfma(a[u], gg, v);
                    }
                }
#pragma unroll
                for (int u = 0; u < 8; ++u) B[ts][r][pbase + u] = a[u];
            }
        }
    }
    __syncthreads();

    // ---- phase 2: H conv ----
    int pj = tid & 15;
    int ct = (tid >> 4) & 7;
    int ts = tid >> 7;               // 0..4
    int hb = ct * OPT;
    float2 acc[OPT];
#pragma unroll
    for (int j = 0; j < OPT; ++j) acc[j] = make_float2(0.f, 0.f);
#pragma unroll
    for (int it = 0; it < WIN; ++it) {
        float2 v = B[ts][hb + it][pj];
#pragma unroll
        for (int j = 0; j < OPT; ++j) {
            int t = it - j;
            if (t >= 0 && t < KS) {
                float2 gg = make_float2(g[t], g[t]);
                acc[j] = pkfma(acc[j], gg, v);
            }
        }
    }
    float* ob = out + (size_t)cd * PLANE + ts * 32 + 2 * pj;
#pragma unroll
    for (int j = 0; j < OPT; ++j)
        *(float2*)(ob + (h0 + hb + j) * NV) = acc[j];
}

// ---------------- streaming D pass (no LDS) ----------------
// thread = (c, d-chunk, h, w-pair): 20 d outputs, 44-load sliding window.
__global__ __launch_bounds__(256) void conv_dp(const float* __restrict__ in,
                                               float* __restrict__ out,
                                               const float* __restrict__ g1) {
    float g[KS];
#pragma unroll
    for (int t = 0; t < KS; ++t) g[t] = g1[t];

    int t0   = blockIdx.x * 256 + threadIdx.x;   // < 3*8*160*80
    int p    = t0 % 80;
    int rem  = t0 / 80;
    int h    = rem % NV;
    int rem2 = rem / NV;
    int dc   = rem2 & 7;
    int c    = rem2 >> 3;

    const float* basep = in + (size_t)c * VOL + h * NV + 2 * p;
    float2 acc[DSEG];
#pragma unroll
    for (int j = 0; j < DSEG; ++j) acc[j] = make_float2(0.f, 0.f);

#pragma unroll
    for (int i = 0; i < DWIN; ++i) {
        int d = dc * DSEG + i - RAD;
        float2 v = make_float2(0.f, 0.f);
        if (d >= 0 && d < NV) v = *(const float2*)(basep + (size_t)d * PLANE);
#pragma unroll
        for (int j = 0; j < DSEG; ++j) {
            int t = i - j;
            if (t >= 0 && t < KS) {
                float2 gg = make_float2(g[t], g[t]);
                acc[j] = pkfma(acc[j], gg, v);
            }
        }
    }
    float* ob = out + (size_t)c * VOL + h * NV + 2 * p;
#pragma unroll
    for (int j = 0; j < DSEG; ++j)
        *(float2*)(ob + (size_t)(dc * DSEG + j) * PLANE) = acc[j];
}

// Fallback (only if ws too small): direct 25^3-tap depthwise conv.
__global__ __launch_bounds__(256) void conv3d_direct(const float* __restrict__ x,
                                                     const float* __restrict__ k3,
                                                     float* __restrict__ out) {
    int idx = blockIdx.x * 256 + threadIdx.x;
    if (idx >= TOT) return;
    int w = idx % NV;
    int t = idx / NV;
    int h = t % NV; t /= NV;
    int d = t % NV;
    int c = t / NV;
    const float* kc = k3 + c * (KS * KS * KS);
    float acc = 0.f;
    for (int i = 0; i < KS; ++i) {
        int dd = d + i - RAD;
        if (dd < 0 || dd >= NV) continue;
        for (int j = 0; j < KS; ++j) {
            int hh = h + j - RAD;
            if (hh < 0 || hh >= NV) continue;
            const float* xr = x + (c * NV + dd) * NV * NV + hh * NV + (w - RAD);
            const float* kr = kc + (i * KS + j) * KS;
            int k0 = (RAD - w) > 0 ? (RAD - w) : 0;
            int k1 = (NV + RAD - w) < KS ? (NV + RAD - w) : KS;
            for (int k = k0; k < k1; ++k) acc += kr[k] * xr[k];
        }
    }
    out[idx] = acc;
}

extern "C" void kernel_launch(void* const* d_in, const int* in_sizes, int n_in,
                              void* d_out, int out_size, void* d_ws, size_t ws_size,
                              hipStream_t stream) {
    const float* x  = (const float*)d_in[0];
    const float* k3 = (const float*)d_in[1];
    float* out = (float*)d_out;

    size_t need = 4096 + (size_t)TOT * sizeof(float);
    if (ws_size >= need) {
        float* g1  = (float*)d_ws;
        float* tmp = (float*)((char*)d_ws + 4096);
        extract_g1<<<KS, 64, 0, stream>>>(k3, g1);
        conv_wh<<<960, 640, 0, stream>>>(x, tmp, g1);        // x   -> tmp (W+H)
        conv_dp<<<1200, 256, 0, stream>>>(tmp, out, g1);     // tmp -> out (D)
    } else {
        conv3d_direct<<<(TOT + 255) / 256, 256, 0, stream>>>(x, k3, out);
    }
}

// Round 4
// 109.808 us; speedup vs baseline: 1.5426x; 1.5426x over previous
//
#include <hip/hip_runtime.h>

// Depthwise 3D Gaussian conv (1,3,160,160,160) fp32, K=25, radius=12.
// Separable. Two main kernels:
//   conv_wh: fused W+H pass per (c,d,h-half); W-conv result held in LDS.
//            320 threads, launch_bounds(320,2) -> no VGPR spill (r3 lesson).
//   conv_d : round-2 LDS-tiled D pass (proven).

#define NV 160
constexpr int KS    = 25;
constexpr int RAD   = 12;
constexpr int PLANE = NV * NV;        // 25600
constexpr int VOL   = NV * NV * NV;   // 4,096,000
constexpr int TOT   = 3 * VOL;        // 12,288,000

// conv_wh geometry
constexpr int HH    = 80;             // h-half
constexpr int BR    = HH + 2 * RAD;   // 104 LDS rows
constexpr int NT    = 5;              // 5 w-tiles of 32
constexpr int TP    = 17;             // float2 pitch per tile row
constexpr int OPT   = 10;             // h outputs/thread (phase 2)
constexpr int WIN   = OPT + KS - 1;   // 34
constexpr int SEG   = 16;             // w outputs/task (phase 1)
constexpr int P1T   = BR * (NV / SEG);// 1040 phase-1 tasks

// conv_d geometry (round-2)
constexpr int ROWS  = NV + 2 * RAD;   // 184
constexpr int PITCH = 17;

__device__ __forceinline__ float2 pkfma(float2 acc, float2 g2, float2 v) {
    asm("v_pk_fma_f32 %0, %1, %2, %0" : "+v"(acc) : "v"(g2), "v"(v));
    return acc;
}

// g1[i] = sum_{j,k} g3[i,j,k]  (since sum(g1)=1).
__global__ void extract_g1(const float* __restrict__ k3, float* __restrict__ g1) {
    int i = blockIdx.x;
    int t = threadIdx.x;
    float s = 0.f;
    for (int e = t; e < KS * KS; e += 64) s += k3[i * KS * KS + e];
#pragma unroll
    for (int off = 32; off > 0; off >>= 1) s += __shfl_down(s, off);
    if (t == 0) g1[i] = s;
}

// ---------------- fused W+H pass ----------------
__global__ __launch_bounds__(320, 2) void conv_wh(const float* __restrict__ in,
                                                  float* __restrict__ out,
                                                  const float* __restrict__ g1) {
    __shared__ float2 B[NT][BR][TP];   // 70720 B
    float g[KS];
#pragma unroll
    for (int t = 0; t < KS; ++t) g[t] = g1[t];

    int tid  = threadIdx.x;
    int b    = blockIdx.x;
    int half = b & 1;
    int cd   = b >> 1;               // c*160 + d
    int h0   = half * HH;
    const float* base = in + (size_t)cd * PLANE;

    // ---- phase 1: W conv from global into LDS ----
#pragma unroll
    for (int iter = 0; iter < 4; ++iter) {
        int task = iter * 320 + tid;
        if (task < P1T) {
            int r = task % BR;       // LDS row
            int s = task / BR;       // w segment (0..9)
            int h = h0 + r - RAD;
            int ts    = s >> 1;
            int pbase = (s & 1) * 8;
            if (h < 0 || h >= NV) {
                float2 z = make_float2(0.f, 0.f);
#pragma unroll
                for (int u = 0; u < 8; ++u) B[ts][r][pbase + u] = z;
            } else {
                const float* rp = base + h * NV;
                float buf[SEG + 28];     // w' in [16s-16, 16s+28)
#pragma unroll
                for (int f = 0; f < 11; ++f) {
                    int lo = SEG * s - 16 + 4 * f;
                    if (lo >= 0 && lo <= NV - 4) {
                        const float4 v = *(const float4*)(rp + lo);
                        buf[4*f+0] = v.x; buf[4*f+1] = v.y;
                        buf[4*f+2] = v.z; buf[4*f+3] = v.w;
                    } else {
                        buf[4*f+0] = 0.f; buf[4*f+1] = 0.f;
                        buf[4*f+2] = 0.f; buf[4*f+3] = 0.f;
                    }
                }
                float2 a[8];
#pragma unroll
                for (int u = 0; u < 8; ++u) a[u] = make_float2(0.f, 0.f);
#pragma unroll
                for (int t = 0; t < KS; ++t) {
                    float2 gg = make_float2(g[t], g[t]);
#pragma unroll
                    for (int u = 0; u < 8; ++u) {
                        float2 v = make_float2(buf[2*u + t + 4], buf[2*u + t + 5]);
                        a[u] = pkfma(a[u], gg, v);
                    }
                }
#pragma unroll
                for (int u = 0; u < 8; ++u) B[ts][r][pbase + u] = a[u];
            }
        }
    }
    __syncthreads();

    // ---- phase 2: H conv from LDS, 2 iterations x 320 threads = 640 tasks --
#pragma unroll
    for (int iter = 0; iter < 2; ++iter) {
        int task = iter * 320 + tid;
        int pj = task & 15;
        int ct = (task >> 4) & 7;
        int ts = task >> 7;          // 0..4
        int hb = ct * OPT;
        float2 acc[OPT];
#pragma unroll
        for (int j = 0; j < OPT; ++j) acc[j] = make_float2(0.f, 0.f);
#pragma unroll
        for (int it = 0; it < WIN; ++it) {
            float2 v = B[ts][hb + it][pj];
#pragma unroll
            for (int j = 0; j < OPT; ++j) {
                int t = it - j;
                if (t >= 0 && t < KS) {
                    float2 gg = make_float2(g[t], g[t]);
                    acc[j] = pkfma(acc[j], gg, v);
                }
            }
        }
        float* ob = out + (size_t)cd * PLANE + ts * 32 + 2 * pj;
#pragma unroll
        for (int j = 0; j < OPT; ++j)
            *(float2*)(ob + (h0 + hb + j) * NV) = acc[j];
    }
}

// ---------------- D pass (round-2, LDS-tiled) ----------------
__global__ __launch_bounds__(256) void conv_d(const float* __restrict__ in,
                                              float* __restrict__ out,
                                              const float* __restrict__ g1) {
    __shared__ float2 T[ROWS][PITCH];
    float2 g2[KS];
#pragma unroll
    for (int t = 0; t < KS; ++t) { float g = g1[t]; g2[t] = make_float2(g, g); }

    int tid = threadIdx.x;
    int b   = blockIdx.x;
    int wt  = b % 5;
    int ch  = b / 5;               // c*160 + h
    int c   = ch / NV, h = ch % NV;
    int w0  = wt * 32;
    const float* base = in + (size_t)c * VOL + h * NV + w0;

    int p  = tid & 15;
    int ct = tid >> 4;
#pragma unroll
    for (int i = ct; i < ROWS; i += 16) {
        int d = i - RAD;
        float2 v = make_float2(0.f, 0.f);
        if (d >= 0 && d < NV) v = *(const float2*)(base + (size_t)d * PLANE + 2 * p);
        T[i][p] = v;
    }
    __syncthreads();

    int db = ct * OPT;
    float2 acc[OPT];
#pragma unroll
    for (int j = 0; j < OPT; ++j) acc[j] = make_float2(0.f, 0.f);
#pragma unroll
    for (int it = 0; it < WIN; ++it) {
        float2 v = T[db + it][p];
#pragma unroll
        for (int j = 0; j < OPT; ++j) {
            int t = it - j;
            if (t >= 0 && t < KS) acc[j] = pkfma(acc[j], g2[t], v);
        }
    }
    float* ob = out + (size_t)c * VOL + h * NV + w0 + 2 * p;
#pragma unroll
    for (int j = 0; j < OPT; ++j)
        *(float2*)(ob + (size_t)(db + j) * PLANE) = acc[j];
}

// Fallback (only if ws too small): direct 25^3-tap depthwise conv.
__global__ __launch_bounds__(256) void conv3d_direct(const float* __restrict__ x,
                                                     const float* __restrict__ k3,
                                                     float* __restrict__ out) {
    int idx = blockIdx.x * 256 + threadIdx.x;
    if (idx >= TOT) return;
    int w = idx % NV;
    int t = idx / NV;
    int h = t % NV; t /= NV;
    int d = t % NV;
    int c = t / NV;
    const float* kc = k3 + c * (KS * KS * KS);
    float acc = 0.f;
    for (int i = 0; i < KS; ++i) {
        int dd = d + i - RAD;
        if (dd < 0 || dd >= NV) continue;
        for (int j = 0; j < KS; ++j) {
            int hh = h + j - RAD;
            if (hh < 0 || hh >= NV) continue;
            const float* xr = x + (c * NV + dd) * NV * NV + hh * NV + (w - RAD);
            const float* kr = kc + (i * KS + j) * KS;
            int k0 = (RAD - w) > 0 ? (RAD - w) : 0;
            int k1 = (NV + RAD - w) < KS ? (NV + RAD - w) : KS;
            for (int k = k0; k < k1; ++k) acc += kr[k] * xr[k];
        }
    }
    out[idx] = acc;
}

extern "C" void kernel_launch(void* const* d_in, const int* in_sizes, int n_in,
                              void* d_out, int out_size, void* d_ws, size_t ws_size,
                              hipStream_t stream) {
    const float* x  = (const float*)d_in[0];
    const float* k3 = (const float*)d_in[1];
    float* out = (float*)d_out;

    size_t need = 4096 + (size_t)TOT * sizeof(float);
    if (ws_size >= need) {
        float* g1  = (float*)d_ws;
        float* tmp = (float*)((char*)d_ws + 4096);
        extract_g1<<<KS, 64, 0, stream>>>(k3, g1);
        conv_wh<<<960, 320, 0, stream>>>(x, tmp, g1);        // x   -> tmp (W+H)
        conv_d<<<480 * 5, 256, 0, stream>>>(tmp, out, g1);   // tmp -> out (D)
    } else {
        conv3d_direct<<<(TOT + 255) / 256, 256, 0, stream>>>(x, k3, out);
    }
}

// Round 5
// 91.158 us; speedup vs baseline: 1.8582x; 1.2046x over previous
//
#include <hip/hip_runtime.h>

// Depthwise 3D Gaussian conv (1,3,160,160,160) fp32, K=25, radius=12.
// Separable. Two main kernels:
//   conv_wd: fused W+D per (c,h,w-tile32). All windows in LDS (no local
//            arrays except acc[] -> no scratch spill, the r3/r4 disease).
//   conv_h : round-2 LDS-tiled H pass (proven).

#define NV 160
constexpr int KS    = 25;
constexpr int RAD   = 12;
constexpr int PLANE = NV * NV;        // 25600
constexpr int VOL   = NV * NV * NV;   // 4,096,000
constexpr int TOT   = 3 * VOL;        // 12,288,000

// conv_wd geometry
constexpr int WT     = 32;            // w outputs per block
constexpr int WIN_W  = WT + 2 * RAD;  // 56 staged w values
constexpr int DPAIRS = 92;            // 184 padded d rows as float2 pairs
constexpr int RPITCH = 93;            // +1 pad
constexpr int WTROWS = 184;           // Wt rows = d + 12
constexpr int WTP    = 17;            // 16 w-pairs + pad
constexpr int OPT    = 10;            // outputs/thread along conv axis
constexpr int WIN    = OPT + KS - 1;  // 34

// conv_h geometry (round-2)
constexpr int ROWS  = NV + 2 * RAD;   // 184
constexpr int PITCH = 17;

__device__ __forceinline__ float2 pkfma(float2 acc, float2 g2, float2 v) {
    asm("v_pk_fma_f32 %0, %1, %2, %0" : "+v"(acc) : "v"(g2), "v"(v));
    return acc;
}

// g1[i] = sum_{j,k} g3[i,j,k]  (since sum(g1)=1).
__global__ void extract_g1(const float* __restrict__ k3, float* __restrict__ g1) {
    int i = blockIdx.x;
    int t = threadIdx.x;
    float s = 0.f;
    for (int e = t; e < KS * KS; e += 64) s += k3[i * KS * KS + e];
#pragma unroll
    for (int off = 32; off > 0; off >>= 1) s += __shfl_down(s, off);
    if (t == 0) g1[i] = s;
}

// ---------------- fused W+D pass ----------------
// block = (c, h, w-tile of 32). Stage raw x (d full, w tile+halo) into
// R[wi][dpair] (float2 along d). W-conv -> Wt[di][wpair] (float2 along w).
// D-conv (r2 pattern) -> out.
__global__ __launch_bounds__(256) void conv_wd(const float* __restrict__ in,
                                               float* __restrict__ out,
                                               const float* __restrict__ g1) {
    __shared__ float2 R[WIN_W][RPITCH];   // 56*93*8  = 41664 B
    __shared__ float2 Wt[WTROWS][WTP];    // 184*17*8 = 25024 B
    float2 g2[KS];
#pragma unroll
    for (int t = 0; t < KS; ++t) { float g = g1[t]; g2[t] = make_float2(g, g); }

    int tid = threadIdx.x;
    int b   = blockIdx.x;
    int wt  = b % 5;
    int ch  = b / 5;               // c*160 + h
    int c   = ch / NV, h = ch % NV;
    int w0  = wt * WT;
    const float* base = in + (size_t)c * VOL + h * NV;  // + d*PLANE + w

    // ---- stage: R[wi][dp] = {x[2dp-12][w0-12+wi], x[2dp-11][w0-12+wi]} ----
    for (int s = tid; s < WIN_W * DPAIRS; s += 256) {
        int wi = s % WIN_W;
        int dp = s / WIN_W;
        int w  = w0 - RAD + wi;
        int d  = 2 * dp - RAD;
        float2 v = make_float2(0.f, 0.f);
        if (w >= 0 && w < NV) {
            if (d >= 0 && d < NV)         v.x = base[(size_t)d * PLANE + w];
            if (d + 1 >= 0 && d + 1 < NV) v.y = base[(size_t)(d + 1) * PLANE + w];
        }
        R[wi][dp] = v;
    }
    __syncthreads();

    // ---- W conv: task = (q: 8-w group 0..3, dp: d-pair 0..91) ----
#pragma unroll
    for (int it2 = 0; it2 < 2; ++it2) {
        int task = it2 * 256 + tid;
        if (task < 4 * DPAIRS) {
            int dp = task % DPAIRS;
            int q  = task / DPAIRS;
            float2 acc[8];
#pragma unroll
            for (int j = 0; j < 8; ++j) acc[j] = make_float2(0.f, 0.f);
#pragma unroll
            for (int it = 0; it < 32; ++it) {
                float2 v = R[8 * q + it][dp];   // wi = wrel + t
#pragma unroll
                for (int j = 0; j < 8; ++j) {
                    int t = it - j;
                    if (t >= 0 && t < KS) acc[j] = pkfma(acc[j], g2[t], v);
                }
            }
            // repack: acc[j] = {d=2dp-12, d=2dp-11} at wrel=8q+j
            // -> Wt[di = d+12][wp], float2 along w
#pragma unroll
            for (int j = 0; j < 8; j += 2) {
                int wp = 4 * q + (j >> 1);
                Wt[2 * dp    ][wp] = make_float2(acc[j].x, acc[j + 1].x);
                Wt[2 * dp + 1][wp] = make_float2(acc[j].y, acc[j + 1].y);
            }
        }
    }
    __syncthreads();

    // ---- D conv (r2 conv_d compute): 256 tasks exactly ----
    int p  = tid & 15;             // w-pair
    int ct = tid >> 4;             // 0..15
    int db = ct * OPT;
    float2 acc[OPT];
#pragma unroll
    for (int j = 0; j < OPT; ++j) acc[j] = make_float2(0.f, 0.f);
#pragma unroll
    for (int it = 0; it < WIN; ++it) {
        float2 v = Wt[db + it][p];
#pragma unroll
        for (int j = 0; j < OPT; ++j) {
            int t = it - j;
            if (t >= 0 && t < KS) acc[j] = pkfma(acc[j], g2[t], v);
        }
    }
    float* ob = out + (size_t)c * VOL + h * NV + w0 + 2 * p;
#pragma unroll
    for (int j = 0; j < OPT; ++j)
        *(float2*)(ob + (size_t)(db + j) * PLANE) = acc[j];
}

// ---------------- H pass (round-2, LDS-tiled, proven) ----------------
__global__ __launch_bounds__(256) void conv_h(const float* __restrict__ in,
                                              float* __restrict__ out,
                                              const float* __restrict__ g1) {
    __shared__ float2 T[ROWS][PITCH];
    float2 g2[KS];
#pragma unroll
    for (int t = 0; t < KS; ++t) { float g = g1[t]; g2[t] = make_float2(g, g); }

    int tid = threadIdx.x;
    int b   = blockIdx.x;
    int wt  = b % 5;
    int cd  = b / 5;               // c*160 + d
    int w0  = wt * 32;
    const float* base = in + (size_t)cd * PLANE + w0;

    int p  = tid & 15;
    int ct = tid >> 4;             // 0..15
#pragma unroll
    for (int i = ct; i < ROWS; i += 16) {
        int h = i - RAD;
        float2 v = make_float2(0.f, 0.f);
        if (h >= 0 && h < NV) v = *(const float2*)(base + h * NV + 2 * p);
        T[i][p] = v;
    }
    __syncthreads();

    int hb = ct * OPT;
    float2 acc[OPT];
#pragma unroll
    for (int j = 0; j < OPT; ++j) acc[j] = make_float2(0.f, 0.f);
#pragma unroll
    for (int it = 0; it < WIN; ++it) {
        float2 v = T[hb + it][p];
#pragma unroll
        for (int j = 0; j < OPT; ++j) {
            int t = it - j;
            if (t >= 0 && t < KS) acc[j] = pkfma(acc[j], g2[t], v);
        }
    }
    float* ob = out + (size_t)cd * PLANE + w0 + 2 * p;
#pragma unroll
    for (int j = 0; j < OPT; ++j)
        *(float2*)(ob + (hb + j) * NV) = acc[j];
}

// Fallback (only if ws too small): direct 25^3-tap depthwise conv.
__global__ __launch_bounds__(256) void conv3d_direct(const float* __restrict__ x,
                                                     const float* __restrict__ k3,
                                                     float* __restrict__ out) {
    int idx = blockIdx.x * 256 + threadIdx.x;
    if (idx >= TOT) return;
    int w = idx % NV;
    int t = idx / NV;
    int h = t % NV; t /= NV;
    int d = t % NV;
    int c = t / NV;
    const float* kc = k3 + c * (KS * KS * KS);
    float acc = 0.f;
    for (int i = 0; i < KS; ++i) {
        int dd = d + i - RAD;
        if (dd < 0 || dd >= NV) continue;
        for (int j = 0; j < KS; ++j) {
            int hh = h + j - RAD;
            if (hh < 0 || hh >= NV) continue;
            const float* xr = x + (c * NV + dd) * NV * NV + hh * NV + (w - RAD);
            const float* kr = kc + (i * KS + j) * KS;
            int k0 = (RAD - w) > 0 ? (RAD - w) : 0;
            int k1 = (NV + RAD - w) < KS ? (NV + RAD - w) : KS;
            for (int k = k0; k < k1; ++k) acc += kr[k] * xr[k];
        }
    }
    out[idx] = acc;
}

extern "C" void kernel_launch(void* const* d_in, const int* in_sizes, int n_in,
                              void* d_out, int out_size, void* d_ws, size_t ws_size,
                              hipStream_t stream) {
    const float* x  = (const float*)d_in[0];
    const float* k3 = (const float*)d_in[1];
    float* out = (float*)d_out;

    size_t need = 4096 + (size_t)TOT * sizeof(float);
    if (ws_size >= need) {
        float* g1  = (float*)d_ws;
        float* tmp = (float*)((char*)d_ws + 4096);
        extract_g1<<<KS, 64, 0, stream>>>(k3, g1);
        conv_wd<<<3 * NV * 5, 256, 0, stream>>>(x, tmp, g1);  // x   -> tmp (W+D)
        conv_h<<<480 * 5, 256, 0, stream>>>(tmp, out, g1);    // tmp -> out (H)
    } else {
        conv3d_direct<<<(TOT + 255) / 256, 256, 0, stream>>>(x, k3, out);
    }
}

// Round 6
// 69.546 us; speedup vs baseline: 2.4357x; 1.3108x over previous
//
#include <hip/hip_runtime.h>

// Depthwise 3D Gaussian conv (1,3,160,160,160) fp32, K=25, radius=12.
// Separable -> three 1-D passes (r2 structure, proven fastest; fusion
// attempts r3-r5 were latency-bound at <=2 blocks/CU and lost).
// This round: g1 recovered in-register per block (no extract kernel),
// float4 tiles for H/D passes, paired stores for W pass.

#define NV 160
constexpr int KS    = 25;
constexpr int RAD   = 12;
constexpr int PLANE = NV * NV;        // 25600
constexpr int VOL   = NV * NV * NV;   // 4,096,000
constexpr int TOT   = 3 * VOL;        // 12,288,000
constexpr int ROWS  = NV + 2 * RAD;   // 184

// W-pass geometry (r2)
constexpr int PITCH = 17;             // float2 pitch
constexpr int OPT   = 10;
constexpr int WIN   = OPT + KS - 1;   // 34

// H/D-pass geometry (float4)
constexpr int QP    = 9;              // float4 pitch (8 quads + pad)
constexpr int OPT4  = 5;              // quad-outputs per thread
constexpr int WIN4  = OPT4 + KS - 1;  // 29

__device__ __forceinline__ void pk(float2& a, float2 g, float2 v) {
    asm("v_pk_fma_f32 %0, %1, %2, %0" : "+v"(a) : "v"(g), "v"(v));
}

// Recover g1[t] from k3: g1[t] = g3[t,12,12] / cbrt(g3[12,12,12])^2 (exact).
__device__ __forceinline__ void load_g(const float* __restrict__ k3, float* g) {
    float c   = k3[12 * 625 + 312];          // g1[12]^3
    float g12 = cbrtf(c);
    float inv = 1.0f / (g12 * g12);
#pragma unroll
    for (int t = 0; t < KS; ++t) g[t] = k3[t * 625 + 312] * inv;
}

// ---------------- W pass (r2 transposed-stage, paired stores) ----------------
__global__ __launch_bounds__(256) void conv_w(const float* __restrict__ in,
                                              float* __restrict__ out,
                                              const float* __restrict__ k3) {
    __shared__ float2 T[ROWS][PITCH];
    float gs[KS];
    load_g(k3, gs);
    float2 g2[KS];
#pragma unroll
    for (int t = 0; t < KS; ++t) g2[t] = make_float2(gs[t], gs[t]);

    int tid = threadIdx.x;
    int b   = blockIdx.x;
    int ht  = b % 5;
    int cd  = b / 5;               // c*160 + d
    int h0  = ht * 32;
    const float* base = in + (size_t)cd * PLANE;

    // stage transposed: T[wi][hp] = {x[h0+2hp][wi-12], x[h0+2hp+1][wi-12]}
    int wl = tid & 31, hq = tid >> 5;        // wl 0..31, hq 0..7
#pragma unroll
    for (int hh = 0; hh < 2; ++hh) {
        int hp = hq + hh * 8;                // 0..15
        const float* r0 = base + (h0 + 2 * hp) * NV;
#pragma unroll
        for (int ib = 0; ib < ROWS; ib += 32) {
            int i = ib + wl;
            if (i < ROWS) {
                int wv = i - RAD;
                float a = 0.f, bb = 0.f;
                if (wv >= 0 && wv < NV) { a = r0[wv]; bb = r0[NV + wv]; }
                T[i][hp] = make_float2(a, bb);
            }
        }
    }
    __syncthreads();

    int p  = tid & 15;             // h-pair
    int ct = tid >> 4;             // 0..15
    int wb = ct * OPT;
    float2 acc[OPT];
#pragma unroll
    for (int j = 0; j < OPT; ++j) acc[j] = make_float2(0.f, 0.f);
#pragma unroll
    for (int it = 0; it < WIN; ++it) {
        float2 v = T[wb + it][p];
#pragma unroll
        for (int j = 0; j < OPT; ++j) {
            int t = it - j;
            if (t >= 0 && t < KS) pk(acc[j], g2[t], v);
        }
    }
    // paired stores: rows h0+2p and h0+2p+1, w = wb..wb+9
    float* obA = out + (size_t)cd * PLANE + (h0 + 2 * p) * NV + wb;
#pragma unroll
    for (int jj = 0; jj < OPT / 2; ++jj) {
        *(float2*)(obA + 2 * jj)      = make_float2(acc[2*jj].x, acc[2*jj+1].x);
        *(float2*)(obA + NV + 2 * jj) = make_float2(acc[2*jj].y, acc[2*jj+1].y);
    }
}

// ---------------- H pass (float4 tile) ----------------
__global__ __launch_bounds__(256) void conv_h(const float* __restrict__ in,
                                              float* __restrict__ out,
                                              const float* __restrict__ k3) {
    __shared__ float4 T4[ROWS][QP];
    float gs[KS];
    load_g(k3, gs);
    float2 g2[KS];
#pragma unroll
    for (int t = 0; t < KS; ++t) g2[t] = make_float2(gs[t], gs[t]);

    int tid = threadIdx.x;
    int b   = blockIdx.x;
    int wt  = b % 5;
    int cd  = b / 5;               // c*160 + d
    int w0  = wt * 32;
    const float* base = in + (size_t)cd * PLANE + w0;

    int q = tid & 7, r = tid >> 3;           // q 0..7, r 0..31
#pragma unroll
    for (int ib = 0; ib < ROWS; ib += 32) {
        int i = ib + r;
        if (i < ROWS) {
            int h = i - RAD;
            float4 v = make_float4(0.f, 0.f, 0.f, 0.f);
            if (h >= 0 && h < NV) v = *(const float4*)(base + h * NV + 4 * q);
            T4[i][q] = v;
        }
    }
    __syncthreads();

    int wq = tid & 7, ct = tid >> 3;         // ct 0..31
    int hb = ct * OPT4;
    float2 alo[OPT4], ahi[OPT4];
#pragma unroll
    for (int j = 0; j < OPT4; ++j) { alo[j] = make_float2(0.f, 0.f); ahi[j] = alo[j]; }
#pragma unroll
    for (int it = 0; it < WIN4; ++it) {
        float4 v = T4[hb + it][wq];
        float2 vlo = make_float2(v.x, v.y);
        float2 vhi = make_float2(v.z, v.w);
#pragma unroll
        for (int j = 0; j < OPT4; ++j) {
            int t = it - j;
            if (t >= 0 && t < KS) { pk(alo[j], g2[t], vlo); pk(ahi[j], g2[t], vhi); }
        }
    }
    float* ob = out + (size_t)cd * PLANE + w0 + 4 * wq;
#pragma unroll
    for (int j = 0; j < OPT4; ++j)
        *(float4*)(ob + (hb + j) * NV) =
            make_float4(alo[j].x, alo[j].y, ahi[j].x, ahi[j].y);
}

// ---------------- D pass (float4 tile) ----------------
__global__ __launch_bounds__(256) void conv_d(const float* __restrict__ in,
                                              float* __restrict__ out,
                                              const float* __restrict__ k3) {
    __shared__ float4 T4[ROWS][QP];
    float gs[KS];
    load_g(k3, gs);
    float2 g2[KS];
#pragma unroll
    for (int t = 0; t < KS; ++t) g2[t] = make_float2(gs[t], gs[t]);

    int tid = threadIdx.x;
    int b   = blockIdx.x;
    int wt  = b % 5;
    int ch  = b / 5;               // c*160 + h
    int c   = ch / NV, h = ch % NV;
    int w0  = wt * 32;
    const float* base = in + (size_t)c * VOL + h * NV + w0;

    int q = tid & 7, r = tid >> 3;
#pragma unroll
    for (int ib = 0; ib < ROWS; ib += 32) {
        int i = ib + r;
        if (i < ROWS) {
            int d = i - RAD;
            float4 v = make_float4(0.f, 0.f, 0.f, 0.f);
            if (d >= 0 && d < NV) v = *(const float4*)(base + (size_t)d * PLANE + 4 * q);
            T4[i][q] = v;
        }
    }
    __syncthreads();

    int wq = tid & 7, ct = tid >> 3;
    int db = ct * OPT4;
    float2 alo[OPT4], ahi[OPT4];
#pragma unroll
    for (int j = 0; j < OPT4; ++j) { alo[j] = make_float2(0.f, 0.f); ahi[j] = alo[j]; }
#pragma unroll
    for (int it = 0; it < WIN4; ++it) {
        float4 v = T4[db + it][wq];
        float2 vlo = make_float2(v.x, v.y);
        float2 vhi = make_float2(v.z, v.w);
#pragma unroll
        for (int j = 0; j < OPT4; ++j) {
            int t = it - j;
            if (t >= 0 && t < KS) { pk(alo[j], g2[t], vlo); pk(ahi[j], g2[t], vhi); }
        }
    }
    float* ob = out + (size_t)c * VOL + h * NV + w0 + 4 * wq;
#pragma unroll
    for (int j = 0; j < OPT4; ++j)
        *(float4*)(ob + (size_t)(db + j) * PLANE) =
            make_float4(alo[j].x, alo[j].y, ahi[j].x, ahi[j].y);
}

// Fallback (only if ws too small): direct 25^3-tap depthwise conv.
__global__ __launch_bounds__(256) void conv3d_direct(const float* __restrict__ x,
                                                     const float* __restrict__ k3,
                                                     float* __restrict__ out) {
    int idx = blockIdx.x * 256 + threadIdx.x;
    if (idx >= TOT) return;
    int w = idx % NV;
    int t = idx / NV;
    int h = t % NV; t /= NV;
    int d = t % NV;
    int c = t / NV;
    const float* kc = k3 + c * (KS * KS * KS);
    float acc = 0.f;
    for (int i = 0; i < KS; ++i) {
        int dd = d + i - RAD;
        if (dd < 0 || dd >= NV) continue;
        for (int j = 0; j < KS; ++j) {
            int hh = h + j - RAD;
            if (hh < 0 || hh >= NV) continue;
            const float* xr = x + (c * NV + dd) * NV * NV + hh * NV + (w - RAD);
            const float* kr = kc + (i * KS + j) * KS;
            int k0 = (RAD - w) > 0 ? (RAD - w) : 0;
            int k1 = (NV + RAD - w) < KS ? (NV + RAD - w) : KS;
            for (int k = k0; k < k1; ++k) acc += kr[k] * xr[k];
        }
    }
    out[idx] = acc;
}

extern "C" void kernel_launch(void* const* d_in, const int* in_sizes, int n_in,
                              void* d_out, int out_size, void* d_ws, size_t ws_size,
                              hipStream_t stream) {
    const float* x  = (const float*)d_in[0];
    const float* k3 = (const float*)d_in[1];
    float* out = (float*)d_out;

    if (ws_size >= (size_t)TOT * sizeof(float)) {
        float* tmp = (float*)d_ws;
        conv_w<<<2400, 256, 0, stream>>>(x, out, k3);    // x   -> out (W)
        conv_h<<<2400, 256, 0, stream>>>(out, tmp, k3);  // out -> tmp (H)
        conv_d<<<2400, 256, 0, stream>>>(tmp, out, k3);  // tmp -> out (D)
    } else {
        conv3d_direct<<<(TOT + 255) / 256, 256, 0, stream>>>(x, k3, out);
    }
}

// Round 7
// 57.435 us; speedup vs baseline: 2.9493x; 1.2109x over previous
//
#include <hip/hip_runtime.h>
#include <hip/hip_fp16.h>

// Depthwise 3D Gaussian conv (1,3,160,160,160) fp32, K=25, radius=12.
// Separable -> three 1-D passes (r2/r6 structure). This round: fp16
// intermediate volumes (compute stays fp32) to cut fabric traffic
// 294 -> 196 MB; passes are BW-bound (r6 post-mortem).

#define NV 160
constexpr int KS    = 25;
constexpr int RAD   = 12;
constexpr int PLANE = NV * NV;        // 25600
constexpr int VOL   = NV * NV * NV;   // 4,096,000
constexpr int TOT   = 3 * VOL;        // 12,288,000
constexpr int ROWS  = NV + 2 * RAD;   // 184

// W-pass geometry
constexpr int PITCH = 17;             // float2 pitch
constexpr int OPT   = 10;
constexpr int WIN   = OPT + KS - 1;   // 34

// H/D-pass geometry (float4 tiles)
constexpr int QP    = 9;              // float4 pitch (8 quads + pad)
constexpr int OPT4  = 5;              // quad-outputs per thread
constexpr int WIN4  = OPT4 + KS - 1;  // 29

__device__ __forceinline__ void pk(float2& a, float2 g, float2 v) {
    asm("v_pk_fma_f32 %0, %1, %2, %0" : "+v"(a) : "v"(g), "v"(v));
}

// Recover g1[t] from k3: g1[t] = g3[t,12,12] / cbrt(g3[12,12,12])^2 (exact).
__device__ __forceinline__ void load_g(const float* __restrict__ k3, float* g) {
    float c   = k3[12 * 625 + 312];          // g1[12]^3
    float g12 = cbrtf(c);
    float inv = 1.0f / (g12 * g12);
#pragma unroll
    for (int t = 0; t < KS; ++t) g[t] = k3[t * 625 + 312] * inv;
}

// ---------------- W pass: f32 in -> f16 out ----------------
__global__ __launch_bounds__(256) void conv_w(const float* __restrict__ in,
                                              __half* __restrict__ out,
                                              const float* __restrict__ k3) {
    __shared__ float2 T[ROWS][PITCH];
    float gs[KS];
    load_g(k3, gs);
    float2 g2[KS];
#pragma unroll
    for (int t = 0; t < KS; ++t) g2[t] = make_float2(gs[t], gs[t]);

    int tid = threadIdx.x;
    int b   = blockIdx.x;
    int ht  = b % 5;
    int cd  = b / 5;               // c*160 + d
    int h0  = ht * 32;
    const float* base = in + (size_t)cd * PLANE;

    // stage transposed: T[wi][hp] = {x[h0+2hp][wi-12], x[h0+2hp+1][wi-12]}
    int wl = tid & 31, hq = tid >> 5;        // wl 0..31, hq 0..7
#pragma unroll
    for (int hh = 0; hh < 2; ++hh) {
        int hp = hq + hh * 8;                // 0..15
        const float* r0 = base + (h0 + 2 * hp) * NV;
#pragma unroll
        for (int ib = 0; ib < ROWS; ib += 32) {
            int i = ib + wl;
            if (i < ROWS) {
                int wv = i - RAD;
                float a = 0.f, bb = 0.f;
                if (wv >= 0 && wv < NV) { a = r0[wv]; bb = r0[NV + wv]; }
                T[i][hp] = make_float2(a, bb);
            }
        }
    }
    __syncthreads();

    int p  = tid & 15;             // h-pair
    int ct = tid >> 4;             // 0..15
    int wb = ct * OPT;
    float2 acc[OPT];
#pragma unroll
    for (int j = 0; j < OPT; ++j) acc[j] = make_float2(0.f, 0.f);
#pragma unroll
    for (int it = 0; it < WIN; ++it) {
        float2 v = T[wb + it][p];
#pragma unroll
        for (int j = 0; j < OPT; ++j) {
            int t = it - j;
            if (t >= 0 && t < KS) pk(acc[j], g2[t], v);
        }
    }
    // paired stores: rows h0+2p and h0+2p+1, w = wb..wb+9 (half2 = 4B)
    __half* obA = out + (size_t)cd * PLANE + (h0 + 2 * p) * NV + wb;
#pragma unroll
    for (int jj = 0; jj < OPT / 2; ++jj) {
        *(__half2*)(obA + 2 * jj) =
            __float22half2_rn(make_float2(acc[2*jj].x, acc[2*jj+1].x));
        *(__half2*)(obA + NV + 2 * jj) =
            __float22half2_rn(make_float2(acc[2*jj].y, acc[2*jj+1].y));
    }
}

// ---------------- H pass: f16 in -> f16 out ----------------
__global__ __launch_bounds__(256) void conv_h(const __half* __restrict__ in,
                                              __half* __restrict__ out,
                                              const float* __restrict__ k3) {
    __shared__ float4 T4[ROWS][QP];
    float gs[KS];
    load_g(k3, gs);
    float2 g2[KS];
#pragma unroll
    for (int t = 0; t < KS; ++t) g2[t] = make_float2(gs[t], gs[t]);

    int tid = threadIdx.x;
    int b   = blockIdx.x;
    int wt  = b % 5;
    int cd  = b / 5;               // c*160 + d
    int w0  = wt * 32;
    const __half* base = in + (size_t)cd * PLANE + w0;

    int q = tid & 7, r = tid >> 3;           // q 0..7, r 0..31
#pragma unroll
    for (int ib = 0; ib < ROWS; ib += 32) {
        int i = ib + r;
        if (i < ROWS) {
            int h = i - RAD;
            float4 v = make_float4(0.f, 0.f, 0.f, 0.f);
            if (h >= 0 && h < NV) {
                const __half2* p2 = (const __half2*)(base + h * NV + 4 * q);
                float2 lo = __half22float2(p2[0]);
                float2 hi = __half22float2(p2[1]);
                v = make_float4(lo.x, lo.y, hi.x, hi.y);
            }
            T4[i][q] = v;
        }
    }
    __syncthreads();

    int wq = tid & 7, ct = tid >> 3;         // ct 0..31
    int hb = ct * OPT4;
    float2 alo[OPT4], ahi[OPT4];
#pragma unroll
    for (int j = 0; j < OPT4; ++j) { alo[j] = make_float2(0.f, 0.f); ahi[j] = alo[j]; }
#pragma unroll
    for (int it = 0; it < WIN4; ++it) {
        float4 v = T4[hb + it][wq];
        float2 vlo = make_float2(v.x, v.y);
        float2 vhi = make_float2(v.z, v.w);
#pragma unroll
        for (int j = 0; j < OPT4; ++j) {
            int t = it - j;
            if (t >= 0 && t < KS) { pk(alo[j], g2[t], vlo); pk(ahi[j], g2[t], vhi); }
        }
    }
    __half* ob = out + (size_t)cd * PLANE + w0 + 4 * wq;
#pragma unroll
    for (int j = 0; j < OPT4; ++j) {
        __half2 o01 = __float22half2_rn(make_float2(alo[j].x, alo[j].y));
        __half2 o23 = __float22half2_rn(make_float2(ahi[j].x, ahi[j].y));
        __half* pdst = ob + (hb + j) * NV;
        *(__half2*)(pdst)     = o01;
        *(__half2*)(pdst + 2) = o23;
    }
}

// ---------------- D pass: f16 in -> f32 out ----------------
__global__ __launch_bounds__(256) void conv_d(const __half* __restrict__ in,
                                              float* __restrict__ out,
                                              const float* __restrict__ k3) {
    __shared__ float4 T4[ROWS][QP];
    float gs[KS];
    load_g(k3, gs);
    float2 g2[KS];
#pragma unroll
    for (int t = 0; t < KS; ++t) g2[t] = make_float2(gs[t], gs[t]);

    int tid = threadIdx.x;
    int b   = blockIdx.x;
    int wt  = b % 5;
    int ch  = b / 5;               // c*160 + h
    int c   = ch / NV, h = ch % NV;
    int w0  = wt * 32;
    const __half* base = in + (size_t)c * VOL + h * NV + w0;

    int q = tid & 7, r = tid >> 3;
#pragma unroll
    for (int ib = 0; ib < ROWS; ib += 32) {
        int i = ib + r;
        if (i < ROWS) {
            int d = i - RAD;
            float4 v = make_float4(0.f, 0.f, 0.f, 0.f);
            if (d >= 0 && d < NV) {
                const __half2* p2 = (const __half2*)(base + (size_t)d * PLANE + 4 * q);
                float2 lo = __half22float2(p2[0]);
                float2 hi = __half22float2(p2[1]);
                v = make_float4(lo.x, lo.y, hi.x, hi.y);
            }
            T4[i][q] = v;
        }
    }
    __syncthreads();

    int wq = tid & 7, ct = tid >> 3;
    int db = ct * OPT4;
    float2 alo[OPT4], ahi[OPT4];
#pragma unroll
    for (int j = 0; j < OPT4; ++j) { alo[j] = make_float2(0.f, 0.f); ahi[j] = alo[j]; }
#pragma unroll
    for (int it = 0; it < WIN4; ++it) {
        float4 v = T4[db + it][wq];
        float2 vlo = make_float2(v.x, v.y);
        float2 vhi = make_float2(v.z, v.w);
#pragma unroll
        for (int j = 0; j < OPT4; ++j) {
            int t = it - j;
            if (t >= 0 && t < KS) { pk(alo[j], g2[t], vlo); pk(ahi[j], g2[t], vhi); }
        }
    }
    float* ob = out + (size_t)c * VOL + h * NV + w0 + 4 * wq;
#pragma unroll
    for (int j = 0; j < OPT4; ++j)
        *(float4*)(ob + (size_t)(db + j) * PLANE) =
            make_float4(alo[j].x, alo[j].y, ahi[j].x, ahi[j].y);
}

// Fallback (only if ws too small): direct 25^3-tap depthwise conv.
__global__ __launch_bounds__(256) void conv3d_direct(const float* __restrict__ x,
                                                     const float* __restrict__ k3,
                                                     float* __restrict__ out) {
    int idx = blockIdx.x * 256 + threadIdx.x;
    if (idx >= TOT) return;
    int w = idx % NV;
    int t = idx / NV;
    int h = t % NV; t /= NV;
    int d = t % NV;
    int c = t / NV;
    const float* kc = k3 + c * (KS * KS * KS);
    float acc = 0.f;
    for (int i = 0; i < KS; ++i) {
        int dd = d + i - RAD;
        if (dd < 0 || dd >= NV) continue;
        for (int j = 0; j < KS; ++j) {
            int hh = h + j - RAD;
            if (hh < 0 || hh >= NV) continue;
            const float* xr = x + (c * NV + dd) * NV * NV + hh * NV + (w - RAD);
            const float* kr = kc + (i * KS + j) * KS;
            int k0 = (RAD - w) > 0 ? (RAD - w) : 0;
            int k1 = (NV + RAD - w) < KS ? (NV + RAD - w) : KS;
            for (int k = k0; k < k1; ++k) acc += kr[k] * xr[k];
        }
    }
    out[idx] = acc;
}

extern "C" void kernel_launch(void* const* d_in, const int* in_sizes, int n_in,
                              void* d_out, int out_size, void* d_ws, size_t ws_size,
                              hipStream_t stream) {
    const float* x  = (const float*)d_in[0];
    const float* k3 = (const float*)d_in[1];
    float* out = (float*)d_out;

    if (ws_size >= (size_t)TOT * 2 * sizeof(__half)) {
        __half* tmpA = (__half*)d_ws;
        __half* tmpB = tmpA + TOT;
        conv_w<<<2400, 256, 0, stream>>>(x, tmpA, k3);     // f32 -> f16 (W)
        conv_h<<<2400, 256, 0, stream>>>(tmpA, tmpB, k3);  // f16 -> f16 (H)
        conv_d<<<2400, 256, 0, stream>>>(tmpB, out, k3);   // f16 -> f32 (D)
    } else {
        conv3d_direct<<<(TOT + 255) / 256, 256, 0, stream>>>(x, k3, out);
    }
}